// Round 4
// baseline (746.359 us; speedup 1.0000x reference)
//
#include <hip/hip_runtime.h>
#include <cstdint>

#define CIN    512
#define COUT   32
#define IMH    56
#define IMW    56
#define NB     32
#define YT     7          // 8-row output tiles
#define XSTR   40         // k-stride in shorts (80 B: 16B-aligned frags, 2-way-max banks)
#define NTH    256
#define CHUNKS 16
#define WROWS  4          // input rows staged per wave
#define WBUF   (WROWS * 58 * XSTR)   // 9280 shorts = 18560 B per buffer

typedef __attribute__((ext_vector_type(8))) short v8s;   // 8 bf16 = 4 VGPRs
typedef __attribute__((ext_vector_type(4))) float v4f;

__device__ __forceinline__ unsigned short f2bf(float f) {
    unsigned u = __builtin_bit_cast(unsigned, f);
    u += 0x7FFFu + ((u >> 16) & 1u);          // round-to-nearest-even
    return (unsigned short)(u >> 16);
}

// ---------------------------------------------------------------------------
// Weight transform (fp32 OIHW -> bf16 MFMA A-frag order) + BN const table.
// w2[(((c32*9+tap)*2+mt)*64+lane)*8+j] = W[m=mt*16+(lane&15)][k=c32*32+(lane>>4)*8+j][tap]
// bq[c2pair] = {scale0, shift0, scale1, shift1} for channels 2*c2pair, +1
// ---------------------------------------------------------------------------
__global__ void wtransform(const float* __restrict__ cw,
                           const float* __restrict__ bn_w, const float* __restrict__ bn_b,
                           const float* __restrict__ rm,   const float* __restrict__ rv,
                           unsigned short* __restrict__ w2, float4* __restrict__ bq) {
    int idx = blockIdx.x * blockDim.x + threadIdx.x;
    if (idx < 256) {
        int c = idx * 2;
        float s0 = bn_w[c]     * rsqrtf(rv[c]     + 1e-5f);
        float s1 = bn_w[c + 1] * rsqrtf(rv[c + 1] + 1e-5f);
        bq[idx] = make_float4(s0, bn_b[c] - rm[c] * s0, s1, bn_b[c + 1] - rm[c + 1] * s1);
    }
    if (idx >= CHUNKS * 9 * 2 * 64 * 8) return;
    int j    = idx & 7;
    int lane = (idx >> 3) & 63;
    int mt   = (idx >> 9) & 1;
    int tmp  = idx >> 10;
    int tap  = tmp % 9;
    int c32  = tmp / 9;
    int m = mt * 16 + (lane & 15);
    int k = c32 * 32 + (lane >> 4) * 8 + j;
    w2[idx] = f2bf(cw[((size_t)m * CIN + k) * 9 + tap]);
}

// ---------------------------------------------------------------------------
// Fused BN+ReLU+3x3 conv, tap-decomposed MFMA implicit GEMM.
// ZERO barriers: wave w owns output rows y0+2w..y0+2w+1 and stages its own
// 4 input rows (y0+2w-1..y0+2w+2) into a PRIVATE dbuf LDS region. Per-wave
// pipeline: pack(c) [vmcnt0 drain] -> issue batch c+1 -> MFMA(c).
// ---------------------------------------------------------------------------
__global__ __launch_bounds__(NTH, 1)
void conv_mfma(const float* __restrict__ x,
               const unsigned short* __restrict__ w2,
               const float4* __restrict__ bq,
               float* __restrict__ out)
{
    __shared__ __align__(16) unsigned short s_x[4][2][WBUF];  // 148480 B

    const int tid  = threadIdx.x;
    const int lane = tid & 63;
    const int wv   = tid >> 6;
    const int yt   = blockIdx.x;
    const int n    = blockIdx.y;
    const int y0   = yt * 8;
    const int c2   = lane & 15;          // channel-pair id for staging + bq

    // --- per-lane staging slot tables (j = 0..13; 4 rows x 14 xg x 16 c2) ---
    int lbase[14];
    int gofs[14];                         // float-index offset within channel block
    unsigned vmask = 0;
    #pragma unroll
    for (int j = 0; j < 14; ++j) {
        int rest = j * 4 + (lane >> 4);   // 0..55
        int xg = rest % 14;
        int r  = rest / 14;               // 0..3
        int iy = y0 + 2 * wv - 1 + r;
        bool v = (iy >= 0) && (iy < IMH);
        if (v) vmask |= (1u << j);
        lbase[j] = (r * 58 + xg * 4 + 1) * XSTR + c2 * 2;
        gofs[j]  = c2 * 2 * 3136 + (v ? iy : 0) * 56 + xg * 4;
    }

    // --- init: zero halo cols (t=0,57) and out-of-image rows, own region ---
    #pragma unroll
    for (int b = 0; b < 2; ++b) {
        unsigned short* B = &s_x[wv][b][0];
        for (int i = lane; i < 4 * 2 * 20; i += 64) {
            int kq = i % 20;
            int rr = (i / 20) >> 1;
            int t  = ((i / 20) & 1) ? 57 : 0;
            *(unsigned*)&B[(rr * 58 + t) * XSTR + kq * 2] = 0u;
        }
        #pragma unroll
        for (int r = 0; r < 4; ++r) {
            int iy = y0 + 2 * wv - 1 + r;
            if (iy < 0 || iy >= IMH) {
                for (int i = lane; i < 58 * 20; i += 64) {
                    int t = i / 20, kq = i % 20;
                    *(unsigned*)&B[(r * 58 + t) * XSTR + kq * 2] = 0u;
                }
            }
        }
    }
    // no __syncthreads needed anywhere: regions are wave-private

    // --- B-fragment bases (7 tiles of 16 px over this wave's 2 output rows) ---
    int b_base[7];
    v4f acc[7][2];
    const v4f zero4 = {0.f, 0.f, 0.f, 0.f};
    #pragma unroll
    for (int i = 0; i < 7; ++i) {
        int p  = i * 16 + (lane & 15);    // 0..111
        int py = p / 56, px = p % 56;     // py 0..1 within wave strip
        b_base[i] = (py * 58 + px) * XSTR + (lane >> 4) * 8;
        acc[i][0] = zero4;
        acc[i][1] = zero4;
    }

    const float* xn = x + (size_t)n * CIN * 3136;

    // --- batch 0: weights -> aw[0], bn -> bnv, inputs -> va/vb ---
    v8s aw[2][18];
    float4 va[14], vb[14];
    float4 bnv;
    {
        const v8s* wp = (const v8s*)(w2);
        #pragma unroll
        for (int t = 0; t < 9; ++t) {
            aw[0][t * 2]     = wp[t * 128 + lane];
            aw[0][t * 2 + 1] = wp[t * 128 + 64 + lane];
        }
        bnv = bq[c2];
        #pragma unroll
        for (int j = 0; j < 14; ++j) {
            if (vmask & (1u << j)) {
                const float* p = xn + gofs[j];
                va[j] = *(const float4*)p;
                vb[j] = *(const float4*)(p + 3136);
            }
        }
    }

    #pragma unroll 2
    for (int gc = 0; gc < CHUNKS; ++gc) {
        unsigned short* bp = &s_x[wv][gc & 1][0];

        // --- pack chunk gc into private LDS (vmcnt drain of batch gc) ---
        const float sa = bnv.x, sha = bnv.y, sb = bnv.z, shb = bnv.w;
        #pragma unroll
        for (int j = 0; j < 14; ++j) {
            unsigned u[4] = {0u, 0u, 0u, 0u};
            if (vmask & (1u << j)) {
                float a0f = fmaxf(fmaf(va[j].x, sa, sha), 0.f);
                float a1f = fmaxf(fmaf(va[j].y, sa, sha), 0.f);
                float a2f = fmaxf(fmaf(va[j].z, sa, sha), 0.f);
                float a3f = fmaxf(fmaf(va[j].w, sa, sha), 0.f);
                float b0f = fmaxf(fmaf(vb[j].x, sb, shb), 0.f);
                float b1f = fmaxf(fmaf(vb[j].y, sb, shb), 0.f);
                float b2f = fmaxf(fmaf(vb[j].z, sb, shb), 0.f);
                float b3f = fmaxf(fmaf(vb[j].w, sb, shb), 0.f);
                u[0] = (unsigned)f2bf(a0f) | ((unsigned)f2bf(b0f) << 16);
                u[1] = (unsigned)f2bf(a1f) | ((unsigned)f2bf(b1f) << 16);
                u[2] = (unsigned)f2bf(a2f) | ((unsigned)f2bf(b2f) << 16);
                u[3] = (unsigned)f2bf(a3f) | ((unsigned)f2bf(b3f) << 16);
            } else if (!((vmask >> j) & 1u)) {
                continue;   // row pre-zeroed at init, never dirtied
            }
            int base = lbase[j];
            #pragma unroll
            for (int e = 0; e < 4; ++e)
                *(unsigned*)&bp[base + e * XSTR] = u[e];
        }

        // --- issue batch gc+1 (stays in flight across MFMA gc) ---
        if (gc < CHUNKS - 1) {
            const v8s* wp = (const v8s*)(w2 + (size_t)(gc + 1) * 9216);
            #pragma unroll
            for (int t = 0; t < 9; ++t) {
                aw[(gc + 1) & 1][t * 2]     = wp[t * 128 + lane];
                aw[(gc + 1) & 1][t * 2 + 1] = wp[t * 128 + 64 + lane];
            }
            bnv = bq[(gc + 1) * 16 + c2];
            const float* ip = xn + (size_t)(gc + 1) * 32 * 3136;
            #pragma unroll
            for (int j = 0; j < 14; ++j) {
                if (vmask & (1u << j)) {
                    const float* p = ip + gofs[j];
                    va[j] = *(const float4*)p;
                    vb[j] = *(const float4*)(p + 3136);
                }
            }
        }

        // --- MFMA chunk gc from private LDS (weights already drained) ---
        #pragma unroll
        for (int tap = 0; tap < 9; ++tap) {
            const int toff = ((tap / 3) * 58 + (tap % 3)) * XSTR;
            const v8s a0 = aw[gc & 1][tap * 2];
            const v8s a1 = aw[gc & 1][tap * 2 + 1];
            #pragma unroll
            for (int i = 0; i < 7; ++i) {
                v8s b = *(const v8s*)&bp[b_base[i] + toff];
                acc[i][0] = __builtin_amdgcn_mfma_f32_16x16x32_bf16(a0, b, acc[i][0], 0, 0, 0);
                acc[i][1] = __builtin_amdgcn_mfma_f32_16x16x32_bf16(a1, b, acc[i][1], 0, 0, 0);
            }
        }
    }

    // --- epilogue: direct stores, rows y0+2wv..y0+2wv+1 ---
    const int prow = (lane >> 4) * 4;
    #pragma unroll
    for (int i = 0; i < 7; ++i) {
        int p = i * 16 + (lane & 15);
        size_t o0 = (size_t)n * COUT * 3136 + (size_t)(y0 + 2 * wv) * 56 + p;
        #pragma unroll
        for (int mt = 0; mt < 2; ++mt) {
            #pragma unroll
            for (int r = 0; r < 4; ++r) {
                int cout = mt * 16 + prow + r;
                out[o0 + (size_t)cout * 3136] = acc[i][mt][r];
            }
        }
    }
}

extern "C" void kernel_launch(void* const* d_in, const int* in_sizes, int n_in,
                              void* d_out, int out_size, void* d_ws, size_t ws_size,
                              hipStream_t stream) {
    const float* x      = (const float*)d_in[0];
    const float* bn_w   = (const float*)d_in[2];
    const float* bn_b   = (const float*)d_in[3];
    const float* r_mean = (const float*)d_in[4];
    const float* r_var  = (const float*)d_in[5];
    const float* cw     = (const float*)d_in[6];
    float* out = (float*)d_out;
    unsigned short* w2 = (unsigned short*)d_ws;                    // 294912 B
    float4* bq = (float4*)((char*)d_ws + 294912);                  // 4096 B

    wtransform<<<dim3(576), dim3(256), 0, stream>>>(cw, bn_w, bn_b, r_mean, r_var, w2, bq);

    conv_mfma<<<dim3(YT, NB), dim3(NTH), 0, stream>>>(x, w2, bq, out);
}

// Round 5
// 658.962 us; speedup vs baseline: 1.1326x; 1.1326x over previous
//
#include <hip/hip_runtime.h>
#include <cstdint>

#define CIN    512
#define COUT   32
#define IMH    56
#define IMW    56
#define NB     32
#define CHUNKS 16
#define XSTR   40                 // shorts per pixel block (32 k + 8 pad) = 80 B
#define XPROW  (58 * XSTR)        // shorts per packed row = 2320 (4640 B)
#define NTH    256

// pass-1 work decomposition
#define NINT   (NB * CHUNKS * 56 * 14 * 16)   // 6,422,528 interior items
#define NZPB   1140                            // zero uint4-slots per (n,gc)
#define NZ     (NB * CHUNKS * NZPB)            // 583,680
#define NTOT   (NINT + NZ)                     // 7,006,208 = 256 * 27368

typedef __attribute__((ext_vector_type(8))) short v8s;   // 8 bf16 = 4 VGPRs
typedef __attribute__((ext_vector_type(4))) float v4f;

__device__ __forceinline__ unsigned short f2bf(float f) {
    unsigned u = __builtin_bit_cast(unsigned, f);
    u += 0x7FFFu + ((u >> 16) & 1u);          // round-to-nearest-even
    return (unsigned short)(u >> 16);
}

__device__ __forceinline__ void glds16(const void* g, void* l) {
    __builtin_amdgcn_global_load_lds(
        (const __attribute__((address_space(1))) unsigned*)g,
        (__attribute__((address_space(3))) unsigned*)l,
        16, 0, 0);
}

// ---------------------------------------------------------------------------
// Weight transform (fp32 OIHW -> bf16 MFMA A-frag order) + BN const table.
// w2[(((gc*9+tap)*2+mt)*64+lane)*8+j] = W[m=mt*16+(lane&15)][k=gc*32+(lane>>4)*8+j][tap]
// bq[gc*16+c2] = {scale0, shift0, scale1, shift1} for channels gc*32+2*c2, +1
// ---------------------------------------------------------------------------
__global__ void wtransform(const float* __restrict__ cw,
                           const float* __restrict__ bn_w, const float* __restrict__ bn_b,
                           const float* __restrict__ rm,   const float* __restrict__ rv,
                           unsigned short* __restrict__ w2, float4* __restrict__ bq) {
    int idx = blockIdx.x * blockDim.x + threadIdx.x;
    if (idx < 256) {
        int c = idx * 2;
        float s0 = bn_w[c]     * rsqrtf(rv[c]     + 1e-5f);
        float s1 = bn_w[c + 1] * rsqrtf(rv[c + 1] + 1e-5f);
        bq[idx] = make_float4(s0, bn_b[c] - rm[c] * s0, s1, bn_b[c + 1] - rm[c + 1] * s1);
    }
    if (idx >= CHUNKS * 9 * 2 * 64 * 8) return;
    int j    = idx & 7;
    int lane = (idx >> 3) & 63;
    int mt   = (idx >> 9) & 1;
    int tmp  = idx >> 10;
    int tap  = tmp % 9;
    int gc   = tmp / 9;
    int m = mt * 16 + (lane & 15);
    int k = gc * 32 + (lane >> 4) * 8 + j;
    w2[idx] = f2bf(cw[((size_t)m * CIN + k) * 9 + tap]);
}

// ---------------------------------------------------------------------------
// Pass 1: streaming BN+ReLU+bf16 repack into xp[n][gc][ry=0..57][col=0..57][k]
// (ry = input y + 1; col = input x + 1; borders zero-baked; 8-short pad/px).
// Interior item: (n,gc,y,xg,c2) -> 2 float4 reads, pack, 4 u32 writes.
// Zero item: one uint4 = 0 at a border slot. No LDS, no barriers: pure MLP.
// ---------------------------------------------------------------------------
__global__ void bn_relu_pack(const float* __restrict__ x,
                             const float4* __restrict__ bq,
                             unsigned* __restrict__ xp) {
    int idx = blockIdx.x * NTH + threadIdx.x;
    if (idx < NINT) {
        int c2 = idx & 15;
        int r  = idx >> 4;
        int xg = r % 14;  r /= 14;
        int y  = r % 56;  r /= 56;
        int gc = r & 15;
        int n  = r >> 4;

        float4 bn = bq[gc * 16 + c2];
        const float* p = x + ((size_t)(n * CIN + gc * 32 + c2 * 2)) * 3136 + y * 56 + xg * 4;
        float4 va = *(const float4*)p;
        float4 vb = *(const float4*)(p + 3136);

        float a0 = fmaxf(fmaf(va.x, bn.x, bn.y), 0.f);
        float a1 = fmaxf(fmaf(va.y, bn.x, bn.y), 0.f);
        float a2 = fmaxf(fmaf(va.z, bn.x, bn.y), 0.f);
        float a3 = fmaxf(fmaf(va.w, bn.x, bn.y), 0.f);
        float b0 = fmaxf(fmaf(vb.x, bn.z, bn.w), 0.f);
        float b1 = fmaxf(fmaf(vb.y, bn.z, bn.w), 0.f);
        float b2 = fmaxf(fmaf(vb.z, bn.z, bn.w), 0.f);
        float b3 = fmaxf(fmaf(vb.w, bn.z, bn.w), 0.f);

        unsigned* wp = xp + ((size_t)((n * 16 + gc) * 58 + y + 1)) * (XPROW / 2)
                          + (xg * 4 + 1) * (XSTR / 2) + c2;
        wp[0]  = (unsigned)f2bf(a0) | ((unsigned)f2bf(b0) << 16);
        wp[20] = (unsigned)f2bf(a1) | ((unsigned)f2bf(b1) << 16);
        wp[40] = (unsigned)f2bf(a2) | ((unsigned)f2bf(b2) << 16);
        wp[60] = (unsigned)f2bf(a3) | ((unsigned)f2bf(b3) << 16);
    } else if (idx < NTOT) {
        int z = idx - NINT;
        int s = z % NZPB;
        int b = z / NZPB;                 // n*16+gc
        uint4* base = (uint4*)xp + (size_t)b * 58 * 290;
        int off;
        if (s < 580) {                    // full zero rows ry=0 and ry=57
            int ry = (s >= 290) ? 57 : 0;
            off = ry * 290 + (s % 290);
        } else {                          // zero cols 0 and 57 for ry=1..56
            int s2 = s - 580;
            int q = s2 % 5;
            int t = s2 / 5;               // 0..111
            int side = t & 1;
            int ry = 1 + (t >> 1);
            off = ry * 290 + (side ? 57 : 0) * 5 + q;
        }
        base[off] = make_uint4(0u, 0u, 0u, 0u);
    }
}

// ---------------------------------------------------------------------------
// Pass 2: 3x3 conv on packed bf16 via tap-decomposed MFMA implicit GEMM.
// Block (yt, n): 4 output rows y0..y0+3; stages xp rows y0..y0+5 (27840 B,
// contiguous) per chunk via global_load_lds width-16 (no VGPR staging).
// Wave wv computes tiles {wv, wv+4, wv+8[, wv+12]} of 14 16-px tiles.
// ---------------------------------------------------------------------------
__global__ __launch_bounds__(NTH, 3)
void conv_mfma(const unsigned short* __restrict__ xp,
               const unsigned short* __restrict__ w2,
               float* __restrict__ out)
{
    __shared__ __align__(16) unsigned short s_x[6 * XPROW];   // 27840 B

    const int tid  = threadIdx.x;
    const int lane = tid & 63;
    const int wv   = tid >> 6;
    const int yt   = blockIdx.x;       // 0..13
    const int n    = blockIdx.y;       // 0..31
    const int y0   = yt * 4;
    const int ntile = (wv < 2) ? 4 : 3;   // 14 tiles over 4 waves

    int b_base[4];
    v4f acc[4][2];
    const v4f zero4 = {0.f, 0.f, 0.f, 0.f};
    #pragma unroll
    for (int i = 0; i < 4; ++i) {
        int T  = wv + i * 4;
        int p  = T * 16 + (lane & 15);    // 0..223 over 4 rows x 56 cols
        int py = p / 56, px = p % 56;
        b_base[i] = ((py * 58 + px) * XSTR + (lane >> 4) * 8) * 2;   // bytes
        acc[i][0] = zero4;
        acc[i][1] = zero4;
    }

    const char* xsrc = (const char*)(xp + ((size_t)(n * 16) * 58 + y0) * XPROW);

    for (int gc = 0; gc < CHUNKS; ++gc) {
        __syncthreads();                  // WAR: prior MFMA reads done

        // A-fragments for this chunk straight from L2 (w2 is L2-resident)
        v8s aw[18];
        const v8s* wpv = (const v8s*)(w2 + (size_t)gc * 9216);
        #pragma unroll
        for (int t = 0; t < 9; ++t) {
            aw[t * 2]     = wpv[t * 128 + lane];
            aw[t * 2 + 1] = wpv[t * 128 + 64 + lane];
        }

        // stage 6 rows x 4640 B (contiguous) direct to LDS, 16 B/lane
        const char* src = xsrc + (size_t)gc * 58 * XPROW * 2;
        #pragma unroll
        for (int j = 0; j < 7; ++j) {
            int s = j * 256 + tid;
            if (s < 1740)
                glds16(src + (size_t)s * 16, (char*)s_x + j * 4096 + wv * 1024);
        }
        __syncthreads();                  // drains glds + A loads; LDS visible

        #pragma unroll
        for (int tap = 0; tap < 9; ++tap) {
            const int toff = (((tap / 3) * 58 + (tap % 3)) * XSTR) * 2;
            const v8s a0 = aw[tap * 2];
            const v8s a1 = aw[tap * 2 + 1];
            #pragma unroll
            for (int i = 0; i < 4; ++i) {
                if (i < ntile) {
                    v8s b = *(const v8s*)((const char*)s_x + b_base[i] + toff);
                    acc[i][0] = __builtin_amdgcn_mfma_f32_16x16x32_bf16(a0, b, acc[i][0], 0, 0, 0);
                    acc[i][1] = __builtin_amdgcn_mfma_f32_16x16x32_bf16(a1, b, acc[i][1], 0, 0, 0);
                }
            }
        }
    }

    // epilogue: direct stores (each output element owned by one thread)
    const int prow = (lane >> 4) * 4;
    #pragma unroll
    for (int i = 0; i < 4; ++i) {
        if (i >= ntile) break;
        int T  = wv + i * 4;
        int p  = T * 16 + (lane & 15);
        int py = p / 56, px = p % 56;
        size_t o0 = (size_t)n * COUT * 3136 + (size_t)(y0 + py) * 56 + px;
        #pragma unroll
        for (int mt = 0; mt < 2; ++mt) {
            #pragma unroll
            for (int r = 0; r < 4; ++r) {
                int cout = mt * 16 + prow + r;
                out[o0 + (size_t)cout * 3136] = acc[i][mt][r];
            }
        }
    }
}

extern "C" void kernel_launch(void* const* d_in, const int* in_sizes, int n_in,
                              void* d_out, int out_size, void* d_ws, size_t ws_size,
                              hipStream_t stream) {
    const float* x      = (const float*)d_in[0];
    const float* bn_w   = (const float*)d_in[2];
    const float* bn_b   = (const float*)d_in[3];
    const float* r_mean = (const float*)d_in[4];
    const float* r_var  = (const float*)d_in[5];
    const float* cw     = (const float*)d_in[6];
    float* out = (float*)d_out;

    unsigned short* w2 = (unsigned short*)d_ws;                      // 294912 B
    float4* bq = (float4*)((char*)d_ws + 294912);                    // 4096 B
    unsigned* xp = (unsigned*)((char*)d_ws + 294912 + 4096);         // 137.8 MB packed input

    wtransform<<<dim3(576), dim3(256), 0, stream>>>(cw, bn_w, bn_b, r_mean, r_var, w2, bq);

    bn_relu_pack<<<dim3(NTOT / NTH), dim3(NTH), 0, stream>>>(x, bq, xp);

    conv_mfma<<<dim3(14, NB), dim3(NTH), 0, stream>>>((const unsigned short*)xp, w2, out);
}